// Round 1
// baseline (472.966 us; speedup 1.0000x reference)
//
#include <hip/hip_runtime.h>
#include <cstdint>

#define T 512
#define B 256
#define D 128
#define H 256
#define INV2PI 0.15915494309189535f

// ws float offsets
#define WHS_OFF 0          // 32 floats
#define HXS_OFF 64         // T*B = 131072 floats
#define CXF_OFF 131136     // 256 floats
#define ZX_OFF  132096     // aligned start of zx
#define ZX_FLOATS (T * B * 32)  // 4194304

// ---------------- K0: whsum[g][q] = sum_h W[q, 128+h] / (2*pi) ----------------
__global__ __launch_bounds__(256) void k0_whs(const float* __restrict__ Wf, const float* __restrict__ Wi,
                                              const float* __restrict__ Wu, const float* __restrict__ Wo,
                                              float* __restrict__ whs) {
  int tid = threadIdx.x;
  int g = tid >> 6, r = tid & 63, q = r >> 3, part = r & 7;
  const float* W = (g == 0) ? Wf : (g == 1) ? Wi : (g == 2) ? Wu : Wo;
  const float* p = W + q * (D + H) + D + part * 32;
  float s = 0.f;
#pragma unroll
  for (int h = 0; h < 32; ++h) s += p[h];
  s += __shfl_xor(s, 1);
  s += __shfl_xor(s, 2);
  s += __shfl_xor(s, 4);
  if (part == 0) whs[g * 8 + q] = s * INV2PI;
}

// ---------------- K1: zx[t*B+b][g][8] = (x_row . W[g][q,:128] + b + p) / 2pi (q=1..7 in slots 1..7) ---
__global__ __launch_bounds__(256) void k1_gemm(const float* __restrict__ x,
    const float* __restrict__ Wf, const float* __restrict__ bf, const float* __restrict__ pf,
    const float* __restrict__ Wi, const float* __restrict__ bi, const float* __restrict__ pi,
    const float* __restrict__ Wu, const float* __restrict__ bu, const float* __restrict__ pu,
    const float* __restrict__ Wo, const float* __restrict__ bo, const float* __restrict__ po,
    float* __restrict__ zx) {
  __shared__ float wl[4 * 7 * 128];
  __shared__ float offs[4][8];
  int tid = threadIdx.x;
#define STAGE(gi, Wg)                                                                 \
  for (int i = tid; i < 7 * 128; i += 256) {                                          \
    int q = i >> 7, d = i & 127;                                                      \
    wl[(gi) * 896 + i] = Wg[(q + 1) * (D + H) + d] * INV2PI;                          \
  }
  STAGE(0, Wf)
  STAGE(1, Wi)
  STAGE(2, Wu)
  STAGE(3, Wo)
#undef STAGE
  if (tid < 8)       offs[0][tid]      = (bf[tid]      + pf[tid])      * INV2PI;
  else if (tid < 16) offs[1][tid - 8]  = (bi[tid - 8]  + pi[tid - 8])  * INV2PI;
  else if (tid < 24) offs[2][tid - 16] = (bu[tid - 16] + pu[tid - 16]) * INV2PI;
  else if (tid < 32) offs[3][tid - 24] = (bo[tid - 24] + po[tid - 24]) * INV2PI;
  __syncthreads();

  int tb = blockIdx.x * 256 + tid;
  const float4* xr = (const float4*)(x + (size_t)tb * D);
  float acc[4][7];
#pragma unroll
  for (int g = 0; g < 4; ++g)
#pragma unroll
    for (int j = 0; j < 7; ++j) acc[g][j] = offs[g][j + 1];

  const float4* wl4 = (const float4*)wl;
#pragma unroll 4
  for (int k = 0; k < 32; ++k) {
    float4 xv = xr[k];
#pragma unroll
    for (int g = 0; g < 4; ++g)
#pragma unroll
      for (int j = 0; j < 7; ++j) {
        float4 wv = wl4[(g * 7 + j) * 32 + k];
        acc[g][j] = fmaf(xv.x, wv.x, fmaf(xv.y, wv.y, fmaf(xv.z, wv.z, fmaf(xv.w, wv.w, acc[g][j]))));
      }
  }
  float4* zo = (float4*)(zx + (size_t)tb * 32);
#pragma unroll
  for (int g = 0; g < 4; ++g) {
    zo[g * 2 + 0] = make_float4(0.f, acc[g][0], acc[g][1], acc[g][2]);
    zo[g * 2 + 1] = make_float4(acc[g][3], acc[g][4], acc[g][5], acc[g][6]);
  }
}

// ---------------- K2: sequential scan, 4 lanes per chain (one per gate) ----------------
__device__ __forceinline__ float qcos(float x) {
  return __builtin_amdgcn_cosf(__builtin_amdgcn_fractf(x));
}
#define QBCAST(v, CTRL) __int_as_float(__builtin_amdgcn_mov_dpp(__float_as_int(v), (CTRL), 0xF, 0xF, true))

__global__ __launch_bounds__(256) void k2_scan(const float* __restrict__ zx, const float* __restrict__ whs,
                                               const float* __restrict__ hx0, const float* __restrict__ cx0,
                                               float* __restrict__ hxs, float* __restrict__ cxf) {
  int tid = threadIdx.x;
  int g = tid & 3;
  int b = blockIdx.x * 64 + (tid >> 2);

  float w[7];
#pragma unroll
  for (int j = 0; j < 7; ++j) w[j] = whs[g * 8 + 1 + j];
  bool isU = (g == 2);
  float mk = isU ? -2.f : -1.f;   // exp multiplier (pre log2e folding done by __expf)
  float sa = isU ? 2.f : 1.f;     // tanh = 2*sigmoid(2x)-1
  float sb = isU ? -1.f : 0.f;

  float hx = hx0[(size_t)b * H];
  float cx = cx0[(size_t)b * H];

  const float4* zp = (const float4*)zx + ((size_t)b * 8 + (size_t)g * 2);
  float4 zb0[8], zb1[8];
#pragma unroll
  for (int s = 0; s < 8; ++s) {
    zb0[s] = zp[(size_t)s * 2048];
    zb1[s] = zp[(size_t)s * 2048 + 1];
  }

  for (int t0 = 0; t0 < T; t0 += 8) {
#pragma unroll
    for (int s = 0; s < 8; ++s) {
      int t = t0 + s;
      float4 z0 = zb0[s], z1 = zb1[s];
      if (t + 8 < T) {  // prefetch 8 steps ahead into this slot
        zb0[s] = zp[(size_t)(t + 8) * 2048];
        zb1[s] = zp[(size_t)(t + 8) * 2048 + 1];
      }
      float c1 = qcos(fmaf(hx, w[0], z0.y));
      float c2 = qcos(fmaf(hx, w[1], z0.z));
      float c3 = qcos(fmaf(hx, w[2], z0.w));
      float c4 = qcos(fmaf(hx, w[3], z1.x));
      float c5 = qcos(fmaf(hx, w[4], z1.y));
      float c6 = qcos(fmaf(hx, w[5], z1.z));
      float c7 = qcos(fmaf(hx, w[6], z1.w));
      float pr = ((c1 * c2) * (c3 * c4)) * ((c5 * c6) * c7);
      float e = __expf(pr * mk);
      float sv = __builtin_amdgcn_rcpf(1.f + e);
      float val = fmaf(sv, sa, sb);     // sigmoid (f,i,o) or tanh (u)
      float fv = QBCAST(val, 0x00);
      float iv = QBCAST(val, 0x55);
      float gv = QBCAST(val, 0xAA);
      float ov = QBCAST(val, 0xFF);
      cx = fmaf(fv, cx, iv * gv);
      float e2 = __expf(cx * -2.f);
      float tc = fmaf(__builtin_amdgcn_rcpf(1.f + e2), 2.f, -1.f);  // tanh(cx)
      hx = ov * tc;
      if (g == 0) hxs[t * B + b] = hx;
    }
  }
  if (g == 0) cxf[b] = cx;
}

// ---------------- K3: broadcast hx over H into the full output ----------------
__global__ __launch_bounds__(256) void k3_bcast(const float* __restrict__ hxs, const float* __restrict__ cxf,
                                                float4* __restrict__ out) {
  const int TBH4 = (T * B * H) / 4;  // 8388608
  const int BH4 = (B * H) / 4;       // 16384
  const int N4 = TBH4 + 2 * BH4;
  int stride = gridDim.x * blockDim.x;
  for (int i = blockIdx.x * blockDim.x + threadIdx.x; i < N4; i += stride) {
    float v;
    if (i < TBH4)                 v = hxs[i >> 6];
    else if (i < TBH4 + BH4)      v = hxs[(T - 1) * B + ((i - TBH4) >> 6)];
    else                          v = cxf[(i - TBH4 - BH4) >> 6];
    out[i] = make_float4(v, v, v, v);
  }
}

extern "C" void kernel_launch(void* const* d_in, const int* in_sizes, int n_in,
                              void* d_out, int out_size, void* d_ws, size_t ws_size,
                              hipStream_t stream) {
  const float* x   = (const float*)d_in[0];
  const float* hx0 = (const float*)d_in[1];
  const float* cx0 = (const float*)d_in[2];
  const float* Wf = (const float*)d_in[3];  const float* bf = (const float*)d_in[4];  const float* pf = (const float*)d_in[5];
  const float* Wi = (const float*)d_in[6];  const float* bi = (const float*)d_in[7];  const float* pi = (const float*)d_in[8];
  const float* Wu = (const float*)d_in[9];  const float* bu = (const float*)d_in[10]; const float* pu = (const float*)d_in[11];
  const float* Wo = (const float*)d_in[12]; const float* bo = (const float*)d_in[13]; const float* po = (const float*)d_in[14];

  float* wsf = (float*)d_ws;
  float* whs = wsf + WHS_OFF;
  float* hxs = wsf + HXS_OFF;
  float* cxf = wsf + CXF_OFF;
  float* out = (float*)d_out;
  // zx lives in ws if it fits, else in the tail of d_out (only needed before K3 overwrites it)
  float* zx = (ws_size >= (size_t)(ZX_OFF + ZX_FLOATS) * sizeof(float))
                  ? (wsf + ZX_OFF)
                  : (out + ((size_t)out_size - ZX_FLOATS));

  hipLaunchKernelGGL(k0_whs, dim3(1), dim3(256), 0, stream, Wf, Wi, Wu, Wo, whs);
  hipLaunchKernelGGL(k1_gemm, dim3(512), dim3(256), 0, stream,
                     x, Wf, bf, pf, Wi, bi, pi, Wu, bu, pu, Wo, bo, po, zx);
  hipLaunchKernelGGL(k2_scan, dim3(4), dim3(256), 0, stream, zx, whs, hx0, cx0, hxs, cxf);
  hipLaunchKernelGGL(k3_bcast, dim3(2048), dim3(256), 0, stream, hxs, cxf, (float4*)out);
}

// Round 3
// 358.251 us; speedup vs baseline: 1.3202x; 1.3202x over previous
//
#include <hip/hip_runtime.h>
#include <cstdint>

#define T 512
#define B 256
#define D 128
#define H 256
#define INV2PI 0.15915494309189535f

typedef float f32x4 __attribute__((ext_vector_type(4)));

// ws float offsets
#define WHS_OFF 0          // 32 floats
#define HXS_OFF 64         // T*B = 131072 floats
#define CXF_OFF 131136     // 256 floats
#define ZX_OFF  132096     // aligned start of zx
#define ZX_FLOATS (T * B * 32)  // 4194304

// ---------------- K0: whs[g*8+q] = sum_h W[q, 128+h] / (2*pi) ----------------
__global__ __launch_bounds__(256) void k0_whs(const float* __restrict__ Wf, const float* __restrict__ Wi,
                                              const float* __restrict__ Wu, const float* __restrict__ Wo,
                                              float* __restrict__ whs) {
  int tid = threadIdx.x;
  int g = tid >> 6, r = tid & 63, q = r >> 3, part = r & 7;
  const float* W = (g == 0) ? Wf : (g == 1) ? Wi : (g == 2) ? Wu : Wo;
  const float* p = W + q * (D + H) + D + part * 32;
  float s = 0.f;
#pragma unroll
  for (int h = 0; h < 32; ++h) s += p[h];
  s += __shfl_xor(s, 1);
  s += __shfl_xor(s, 2);
  s += __shfl_xor(s, 4);
  if (part == 0) whs[g * 8 + q] = s * INV2PI;
}

// ---------------- K1: zx[(t*B+b)*32 + g*8 + q] = (x . W[g][q,:128] + b + p)/2pi ----------------
// W reads are wave-uniform -> scalar s_load path; no LDS at all.
__global__ __launch_bounds__(256) void k1_gemm(const float* __restrict__ x,
    const float* __restrict__ Wf, const float* __restrict__ bf, const float* __restrict__ pf,
    const float* __restrict__ Wi, const float* __restrict__ bi, const float* __restrict__ pi,
    const float* __restrict__ Wu, const float* __restrict__ bu, const float* __restrict__ pu,
    const float* __restrict__ Wo, const float* __restrict__ bo, const float* __restrict__ po,
    float* __restrict__ zx) {
  int tid = threadIdx.x;
  int tb = blockIdx.x * 256 + tid;
  const float4* xr = (const float4*)(x + (size_t)tb * D);

  const float* Ws[4] = {Wf, Wi, Wu, Wo};
  const float* bs[4] = {bf, bi, bu, bo};
  const float* ps[4] = {pf, pi, pu, po};

  float acc[4][7];
#pragma unroll
  for (int g = 0; g < 4; ++g)
#pragma unroll
    for (int j = 0; j < 7; ++j) acc[g][j] = 0.f;

#pragma unroll 2
  for (int k = 0; k < 32; ++k) {
    float4 xv = xr[k];
#pragma unroll
    for (int g = 0; g < 4; ++g) {
#pragma unroll
      for (int j = 0; j < 7; ++j) {
        const float4 wv = *(const float4*)(Ws[g] + (size_t)(j + 1) * (D + H) + k * 4);  // uniform -> s_load
        acc[g][j] = fmaf(xv.x, wv.x, fmaf(xv.y, wv.y, fmaf(xv.z, wv.z, fmaf(xv.w, wv.w, acc[g][j]))));
      }
    }
  }

  float4* zo = (float4*)(zx + (size_t)tb * 32);
#pragma unroll
  for (int g = 0; g < 4; ++g) {
    float z[7];
#pragma unroll
    for (int j = 0; j < 7; ++j)
      z[j] = fmaf(acc[g][j], INV2PI, (bs[g][j + 1] + ps[g][j + 1]) * INV2PI);
    zo[g * 2 + 0] = make_float4(0.f, z[0], z[1], z[2]);
    zo[g * 2 + 1] = make_float4(z[3], z[4], z[5], z[6]);
  }
}

// ---------------- K2: sequential scan, 4 lanes per chain (one per gate) ----------------
__device__ __forceinline__ float qcos(float x) {
  return __builtin_amdgcn_cosf(__builtin_amdgcn_fractf(x));
}
#define QBCAST(v, CTRL) __int_as_float(__builtin_amdgcn_mov_dpp(__float_as_int(v), (CTRL), 0xF, 0xF, true))

// One STEP of the recurrence; named float4 prefetch registers (NO arrays -> no scratch).
#define STEP(S)                                                            \
  {                                                                        \
    float4 z0 = zA##S, z1 = zB##S;                                         \
    {                                                                      \
      size_t toff = (size_t)((t0 + S + 8) & (T - 1)) * 2048;               \
      zA##S = zp[toff];                                                    \
      zB##S = zp[toff + 1];                                                \
    }                                                                      \
    float c1 = qcos(fmaf(hx, w[0], z0.y));                                 \
    float c2 = qcos(fmaf(hx, w[1], z0.z));                                 \
    float c3 = qcos(fmaf(hx, w[2], z0.w));                                 \
    float c4 = qcos(fmaf(hx, w[3], z1.x));                                 \
    float c5 = qcos(fmaf(hx, w[4], z1.y));                                 \
    float c6 = qcos(fmaf(hx, w[5], z1.z));                                 \
    float c7 = qcos(fmaf(hx, w[6], z1.w));                                 \
    float pr = ((c1 * c2) * (c3 * c4)) * ((c5 * c6) * c7);                 \
    float e = __expf(pr * mk);                                             \
    float sv = __builtin_amdgcn_rcpf(1.f + e);                             \
    float val = fmaf(sv, sa, sb);                                          \
    float fv = QBCAST(val, 0x00);                                          \
    float iv = QBCAST(val, 0x55);                                          \
    float gv = QBCAST(val, 0xAA);                                          \
    float ov = QBCAST(val, 0xFF);                                          \
    cx = fmaf(fv, cx, iv * gv);                                            \
    float e2 = __expf(cx * -2.f);                                          \
    float tc = fmaf(__builtin_amdgcn_rcpf(1.f + e2), 2.f, -1.f);           \
    hx = ov * tc;                                                          \
    if (g == 0) hxs[(t0 + S) * B + b] = hx;                                \
  }

__global__ __launch_bounds__(64) void k2_scan(const float* __restrict__ zx, const float* __restrict__ whs,
                                              const float* __restrict__ hx0, const float* __restrict__ cx0,
                                              float* __restrict__ hxs, float* __restrict__ cxf) {
  int tid = threadIdx.x;
  int g = tid & 3;
  int b = blockIdx.x * 16 + (tid >> 2);

  float w[7];
#pragma unroll
  for (int j = 0; j < 7; ++j) w[j] = whs[g * 8 + 1 + j];
  bool isU = (g == 2);
  float mk = isU ? -2.f : -1.f;
  float sa = isU ? 2.f : 1.f;
  float sb = isU ? -1.f : 0.f;

  float hx = hx0[(size_t)b * H];
  float cx = cx0[(size_t)b * H];

  const float4* zp = (const float4*)zx + ((size_t)b * 8 + (size_t)g * 2);

  // depth-8 prefetch in 16 NAMED float4 registers
  float4 zA0 = zp[0 * 2048], zB0 = zp[0 * 2048 + 1];
  float4 zA1 = zp[1 * 2048], zB1 = zp[1 * 2048 + 1];
  float4 zA2 = zp[2 * 2048], zB2 = zp[2 * 2048 + 1];
  float4 zA3 = zp[3 * 2048], zB3 = zp[3 * 2048 + 1];
  float4 zA4 = zp[4 * 2048], zB4 = zp[4 * 2048 + 1];
  float4 zA5 = zp[5 * 2048], zB5 = zp[5 * 2048 + 1];
  float4 zA6 = zp[6 * 2048], zB6 = zp[6 * 2048 + 1];
  float4 zA7 = zp[7 * 2048], zB7 = zp[7 * 2048 + 1];

  for (int t0 = 0; t0 < T; t0 += 8) {
    STEP(0)
    STEP(1)
    STEP(2)
    STEP(3)
    STEP(4)
    STEP(5)
    STEP(6)
    STEP(7)
  }
  if (g == 0) cxf[b] = cx;
}

// ---------------- K3: broadcast hx over H into the full output ----------------
__global__ __launch_bounds__(256) void k3_bcast(const float* __restrict__ hxs, const float* __restrict__ cxf,
                                                float* __restrict__ out) {
  const int TBH4 = (T * B * H) / 4;  // 8388608
  const int BH4 = (B * H) / 4;       // 16384
  const int N4 = TBH4 + 2 * BH4;
  f32x4* out4 = (f32x4*)out;
  int stride = gridDim.x * blockDim.x;
  for (int i = blockIdx.x * blockDim.x + threadIdx.x; i < N4; i += stride) {
    float v;
    if (i < TBH4)            v = hxs[i >> 6];
    else if (i < TBH4 + BH4) v = hxs[(T - 1) * B + ((i - TBH4) >> 6)];
    else                     v = cxf[(i - TBH4 - BH4) >> 6];
    f32x4 pv = {v, v, v, v};
    __builtin_nontemporal_store(pv, &out4[i]);
  }
}

extern "C" void kernel_launch(void* const* d_in, const int* in_sizes, int n_in,
                              void* d_out, int out_size, void* d_ws, size_t ws_size,
                              hipStream_t stream) {
  const float* x   = (const float*)d_in[0];
  const float* hx0 = (const float*)d_in[1];
  const float* cx0 = (const float*)d_in[2];
  const float* Wf = (const float*)d_in[3];  const float* bf = (const float*)d_in[4];  const float* pf = (const float*)d_in[5];
  const float* Wi = (const float*)d_in[6];  const float* bi = (const float*)d_in[7];  const float* pi = (const float*)d_in[8];
  const float* Wu = (const float*)d_in[9];  const float* bu = (const float*)d_in[10]; const float* pu = (const float*)d_in[11];
  const float* Wo = (const float*)d_in[12]; const float* bo = (const float*)d_in[13]; const float* po = (const float*)d_in[14];

  float* wsf = (float*)d_ws;
  float* whs = wsf + WHS_OFF;
  float* hxs = wsf + HXS_OFF;
  float* cxf = wsf + CXF_OFF;
  float* out = (float*)d_out;
  float* zx = (ws_size >= (size_t)(ZX_OFF + ZX_FLOATS) * sizeof(float))
                  ? (wsf + ZX_OFF)
                  : (out + ((size_t)out_size - ZX_FLOATS));

  hipLaunchKernelGGL(k0_whs, dim3(1), dim3(256), 0, stream, Wf, Wi, Wu, Wo, whs);
  hipLaunchKernelGGL(k1_gemm, dim3(512), dim3(256), 0, stream,
                     x, Wf, bf, pf, Wi, bi, pi, Wu, bu, pu, Wo, bo, po, zx);
  hipLaunchKernelGGL(k2_scan, dim3(16), dim3(64), 0, stream, zx, whs, hx0, cx0, hxs, cxf);
  hipLaunchKernelGGL(k3_bcast, dim3(4096), dim3(256), 0, stream, hxs, cxf, out);
}

// Round 4
// 347.978 us; speedup vs baseline: 1.3592x; 1.0295x over previous
//
#include <hip/hip_runtime.h>
#include <cstdint>

#define T 512
#define B 256
#define D 128
#define H 256
#define DH 384
#define INV2PI 0.15915494309189535f
#define NLOG2E 1.442695041f

typedef float f32x4 __attribute__((ext_vector_type(4)));

// ws float offsets
#define WHS_OFF 0          // 32 floats
#define HXS_OFF 64         // T*B = 131072 floats
#define CXF_OFF 131136     // 256 floats
#define ZX_OFF  132096     // aligned start of zx
#define ZX_FLOATS (T * B * 32)  // 4194304

// ---------------- K0: whs[g*8+q] = sum_h W[q, 128+h] / (2*pi) ----------------
__global__ __launch_bounds__(256) void k0_whs(const float* __restrict__ Wf, const float* __restrict__ Wi,
                                              const float* __restrict__ Wu, const float* __restrict__ Wo,
                                              float* __restrict__ whs) {
  int tid = threadIdx.x;
  int g = tid >> 6, r = tid & 63, q = r >> 3, part = r & 7;
  const float* W = (g == 0) ? Wf : (g == 1) ? Wi : (g == 2) ? Wu : Wo;
  const float* p = W + q * DH + D + part * 32;
  float s = 0.f;
#pragma unroll
  for (int h = 0; h < 32; ++h) s += p[h];
  s += __shfl_xor(s, 1);
  s += __shfl_xor(s, 2);
  s += __shfl_xor(s, 4);
  if (part == 0) whs[g * 8 + q] = s * INV2PI;
}

// ---------------- K1: zx[(t*B+b)*32 + g*8 + q] = (x . W[g][q,:128] + b + p)/2pi ------------
// W staged in LDS (broadcast reads), 4 rows per thread to amortize LDS traffic.
__global__ __launch_bounds__(128) void k1_gemm(const float* __restrict__ x,
    const float* __restrict__ Wf, const float* __restrict__ bf, const float* __restrict__ pf,
    const float* __restrict__ Wi, const float* __restrict__ bi, const float* __restrict__ pi,
    const float* __restrict__ Wu, const float* __restrict__ bu, const float* __restrict__ pu,
    const float* __restrict__ Wo, const float* __restrict__ bo, const float* __restrict__ po,
    float* __restrict__ zx) {
  __shared__ float wl[28 * 128];   // [(g*7 + (q-1))*128 + d], pre-scaled by 1/2pi
  __shared__ float offs[32];       // (b+p)/2pi, [g*8+q]
  int tid = threadIdx.x;
  const float* Ws[4] = {Wf, Wi, Wu, Wo};
  const float* bs[4] = {bf, bi, bu, bo};
  const float* ps[4] = {pf, pi, pu, po};
#pragma unroll
  for (int g = 0; g < 4; ++g)
    for (int i = tid; i < 896; i += 128) {
      int q = i >> 7, d = i & 127;
      wl[g * 896 + i] = Ws[g][(q + 1) * DH + d] * INV2PI;
    }
  if (tid < 32) {
    int g = tid >> 3, q = tid & 7;
    offs[tid] = (bs[g][q] + ps[g][q]) * INV2PI;
  }
  __syncthreads();

  int row0 = blockIdx.x * 512 + tid;  // rows row0 + {0,128,256,384}
  const float4* x4 = (const float4*)x;
  const float4* wl4 = (const float4*)wl;

  float acc0[28], acc1[28], acc2[28], acc3[28];
#pragma unroll
  for (int r = 0; r < 28; ++r) acc0[r] = acc1[r] = acc2[r] = acc3[r] = 0.f;

  for (int k = 0; k < 32; ++k) {
    float4 xv0 = x4[(size_t)row0 * 32 + k];
    float4 xv1 = x4[(size_t)row0 * 32 + 4096 + k];
    float4 xv2 = x4[(size_t)row0 * 32 + 8192 + k];
    float4 xv3 = x4[(size_t)row0 * 32 + 12288 + k];
#pragma unroll
    for (int r = 0; r < 28; ++r) {
      float4 wv = wl4[r * 32 + k];
      acc0[r] = fmaf(xv0.x, wv.x, fmaf(xv0.y, wv.y, fmaf(xv0.z, wv.z, fmaf(xv0.w, wv.w, acc0[r]))));
      acc1[r] = fmaf(xv1.x, wv.x, fmaf(xv1.y, wv.y, fmaf(xv1.z, wv.z, fmaf(xv1.w, wv.w, acc1[r]))));
      acc2[r] = fmaf(xv2.x, wv.x, fmaf(xv2.y, wv.y, fmaf(xv2.z, wv.z, fmaf(xv2.w, wv.w, acc2[r]))));
      acc3[r] = fmaf(xv3.x, wv.x, fmaf(xv3.y, wv.y, fmaf(xv3.z, wv.z, fmaf(xv3.w, wv.w, acc3[r]))));
    }
  }

#define WROW(ACC, M)                                                                     \
  {                                                                                      \
    float4* zo = (float4*)(zx + (size_t)(row0 + (M)*128) * 32);                          \
    _Pragma("unroll") for (int g = 0; g < 4; ++g) {                                      \
      zo[g * 2 + 0] = make_float4(0.f, ACC[g * 7 + 0] + offs[g * 8 + 1],                 \
                                  ACC[g * 7 + 1] + offs[g * 8 + 2],                      \
                                  ACC[g * 7 + 2] + offs[g * 8 + 3]);                     \
      zo[g * 2 + 1] = make_float4(ACC[g * 7 + 3] + offs[g * 8 + 4],                      \
                                  ACC[g * 7 + 4] + offs[g * 8 + 5],                      \
                                  ACC[g * 7 + 5] + offs[g * 8 + 6],                      \
                                  ACC[g * 7 + 6] + offs[g * 8 + 7]);                     \
    }                                                                                    \
  }
  WROW(acc0, 0) WROW(acc1, 1) WROW(acc2, 2) WROW(acc3, 3)
#undef WROW
}

// ---------------- K2: sequential scan, LDS double-buffered z tiles ----------------
__device__ __forceinline__ float qcos(float x) {
  return __builtin_amdgcn_cosf(__builtin_amdgcn_fractf(x));
}
#define QBCAST(v, CTRL) __int_as_float(__builtin_amdgcn_mov_dpp(__float_as_int(v), (CTRL), 0xF, 0xF, true))

__device__ __forceinline__ void gload16(const float* g, float* l, int tid) {
#if __has_builtin(__builtin_amdgcn_global_load_lds)
  __builtin_amdgcn_global_load_lds((const __attribute__((address_space(1))) unsigned int*)g,
                                   (__attribute__((address_space(3))) unsigned int*)l, 16, 0, 0);
#else
  *(f32x4*)(l + tid * 4) = *(const f32x4*)g;
#endif
}

// stage one 16-step tile (32 x 1KB chunks) into LDS buffer at lbase
__device__ __forceinline__ void stage_tile(const float* gbase, int t0, float* lbase, int tid) {
#pragma unroll
  for (int s = 0; s < 16; ++s) {
    const float* g = gbase + (size_t)(t0 + s) * 8192;
    gload16(g, lbase + s * 512, tid);
    gload16(g + 256, lbase + s * 512 + 256, tid);
  }
}

// One scan step. Consumes (ZA,ZB); issues ds_read prefetch for step S+2 into (ZA,ZB).
#define STEP(S, ZA, ZB, TGT, TOFF)                                         \
  {                                                                        \
    f32x4 z0 = ZA, z1 = ZB;                                                \
    ZA = *(const f32x4*)((TGT) + (TOFF));                                  \
    ZB = *(const f32x4*)((TGT) + (TOFF) + 4);                              \
    float c1 = qcos(fmaf(hx, w[0], z0[1]));                                \
    float c2 = qcos(fmaf(hx, w[1], z0[2]));                                \
    float c3 = qcos(fmaf(hx, w[2], z0[3]));                                \
    float c4 = qcos(fmaf(hx, w[3], z1[0]));                                \
    float c5 = qcos(fmaf(hx, w[4], z1[1]));                                \
    float c6 = qcos(fmaf(hx, w[5], z1[2]));                                \
    float c7 = qcos(fmaf(hx, w[6], z1[3]));                                \
    float d4 = c7 * mk2;                                                   \
    float pr = ((c1 * c2) * (c3 * c4)) * ((c5 * c6) * d4);                 \
    float e = exp2f(pr);                                                   \
    float sv = __builtin_amdgcn_rcpf(1.f + e);                             \
    float val = fmaf(sv, sa, sb);                                          \
    float fv = QBCAST(val, 0x00);                                          \
    float iv = QBCAST(val, 0x55);                                          \
    float gv = QBCAST(val, 0xAA);                                          \
    float ov = QBCAST(val, 0xFF);                                          \
    cx = fmaf(fv, cx, iv * gv);                                            \
    float e2 = exp2f(cx * -2.885390082f);                                  \
    float tc = fmaf(__builtin_amdgcn_rcpf(1.f + e2), 2.f, -1.f);           \
    hx = ov * tc;                                                          \
    h##S = hx;                                                             \
  }

__global__ __launch_bounds__(64) void k2_scan(const float* __restrict__ zx, const float* __restrict__ whs,
                                              const float* __restrict__ hx0, const float* __restrict__ cx0,
                                              float* __restrict__ hxs, float* __restrict__ cxf) {
  __shared__ float zbuf[2 * 16 * 16 * 32];  // 64 KB: [buf][step][chain][32]
  int tid = threadIdx.x;
  int g = tid & 3;
  int c = tid >> 2;
  int b = blockIdx.x * 16 + c;

  float w[7];
#pragma unroll
  for (int j = 0; j < 7; ++j) w[j] = whs[g * 8 + 1 + j];
  bool isU = (g == 2);
  float mk2 = isU ? -2.885390082f : -NLOG2E;  // fold log2e (exp2f) into product leaf
  float sa = isU ? 2.f : 1.f;
  float sb = isU ? -1.f : 0.f;

  float hx = hx0[(size_t)b * H];
  float cx = cx0[(size_t)b * H];

  float* zb = &zbuf[0];
  float* lb = zb + tid * 8;                              // per-lane read base (floats)
  const float* gbase = zx + (size_t)blockIdx.x * 512 + (size_t)tid * 4;  // per-lane stage base

  // prologue: stage tiles 0,1; wait tile0; register-prefetch steps 0,1
  stage_tile(gbase, 0, zb, tid);
  stage_tile(gbase, 16, zb + 8192, tid);
  asm volatile("s_waitcnt vmcnt(32)" ::: "memory");

  f32x4 pA = *(const f32x4*)(lb + 0);        // step 0
  f32x4 pB = *(const f32x4*)(lb + 4);
  f32x4 qA = *(const f32x4*)(lb + 512);      // step 1
  f32x4 qB = *(const f32x4*)(lb + 516);

  float h0, h1, h2, h3, h4, h5, h6, h7, h8, h9, h10, h11, h12, h13, h14, h15;

  for (int kt = 0; kt < 32; ++kt) {
    float* bp = lb + (kt & 1) * 8192;        // current tile buffer (lane base)
    float* bq = lb + ((kt & 1) ^ 1) * 8192;  // next tile buffer

    STEP(0, pA, pB, bp, 2 * 512)
    STEP(1, qA, qB, bp, 3 * 512)
    STEP(2, pA, pB, bp, 4 * 512)
    STEP(3, qA, qB, bp, 5 * 512)
    STEP(4, pA, pB, bp, 6 * 512)
    STEP(5, qA, qB, bp, 7 * 512)
    STEP(6, pA, pB, bp, 8 * 512)
    STEP(7, qA, qB, bp, 9 * 512)
    STEP(8, pA, pB, bp, 10 * 512)
    STEP(9, qA, qB, bp, 11 * 512)
    STEP(10, pA, pB, bp, 12 * 512)
    STEP(11, qA, qB, bp, 13 * 512)
    STEP(12, pA, pB, bp, 14 * 512)
    STEP(13, qA, qB, bp, 15 * 512)
    // ensure next tile's LDS is complete before cross-tile register prefetch
    asm volatile("s_waitcnt vmcnt(0)" ::: "memory");
    STEP(14, pA, pB, bq, 0 * 512)
    STEP(15, qA, qB, bq, 1 * 512)

    // batched hx stores for this tile (after the wait, so they never sit
    // between counted staging loads at the NEXT wait point)
    if (g == 0) {
      float* hp = hxs + (size_t)(kt * 16) * B + b;
      hp[0 * B] = h0;   hp[1 * B] = h1;   hp[2 * B] = h2;   hp[3 * B] = h3;
      hp[4 * B] = h4;   hp[5 * B] = h5;   hp[6 * B] = h6;   hp[7 * B] = h7;
      hp[8 * B] = h8;   hp[9 * B] = h9;   hp[10 * B] = h10; hp[11 * B] = h11;
      hp[12 * B] = h12; hp[13 * B] = h13; hp[14 * B] = h14; hp[15 * B] = h15;
    }

    if (kt + 2 < 32) {
      // drain ds_reads of the buffer we're about to overwrite
      asm volatile("s_waitcnt lgkmcnt(0)" ::: "memory");
      stage_tile(gbase, (kt + 2) * 16, zb + (kt & 1) * 8192, tid);
    }
  }
  if (g == 0) cxf[b] = cx;
}

// ---------------- K3: broadcast hx over H into the full output ----------------
__global__ __launch_bounds__(256) void k3_bcast(const float* __restrict__ hxs, const float* __restrict__ cxf,
                                                float* __restrict__ out) {
  const int TBH4 = (T * B * H) / 4;  // 8388608
  const int BH4 = (B * H) / 4;       // 16384
  const int N4 = TBH4 + 2 * BH4;
  f32x4* out4 = (f32x4*)out;
  int stride = gridDim.x * blockDim.x;
  for (int i = blockIdx.x * blockDim.x + threadIdx.x; i < N4; i += stride) {
    float v;
    if (i < TBH4)            v = hxs[i >> 6];
    else if (i < TBH4 + BH4) v = hxs[(T - 1) * B + ((i - TBH4) >> 6)];
    else                     v = cxf[(i - TBH4 - BH4) >> 6];
    f32x4 pv = {v, v, v, v};
    __builtin_nontemporal_store(pv, &out4[i]);
  }
}

extern "C" void kernel_launch(void* const* d_in, const int* in_sizes, int n_in,
                              void* d_out, int out_size, void* d_ws, size_t ws_size,
                              hipStream_t stream) {
  const float* x   = (const float*)d_in[0];
  const float* hx0 = (const float*)d_in[1];
  const float* cx0 = (const float*)d_in[2];
  const float* Wf = (const float*)d_in[3];  const float* bf = (const float*)d_in[4];  const float* pf = (const float*)d_in[5];
  const float* Wi = (const float*)d_in[6];  const float* bi = (const float*)d_in[7];  const float* pi = (const float*)d_in[8];
  const float* Wu = (const float*)d_in[9];  const float* bu = (const float*)d_in[10]; const float* pu = (const float*)d_in[11];
  const float* Wo = (const float*)d_in[12]; const float* bo = (const float*)d_in[13]; const float* po = (const float*)d_in[14];

  float* wsf = (float*)d_ws;
  float* whs = wsf + WHS_OFF;
  float* hxs = wsf + HXS_OFF;
  float* cxf = wsf + CXF_OFF;
  float* out = (float*)d_out;
  float* zx = (ws_size >= (size_t)(ZX_OFF + ZX_FLOATS) * sizeof(float))
                  ? (wsf + ZX_OFF)
                  : (out + ((size_t)out_size - ZX_FLOATS));

  hipLaunchKernelGGL(k0_whs, dim3(1), dim3(256), 0, stream, Wf, Wi, Wu, Wo, whs);
  hipLaunchKernelGGL(k1_gemm, dim3(256), dim3(128), 0, stream,
                     x, Wf, bf, pf, Wi, bi, pi, Wu, bu, pu, Wo, bo, po, zx);
  hipLaunchKernelGGL(k2_scan, dim3(16), dim3(64), 0, stream, zx, whs, hx0, cx0, hxs, cxf);
  hipLaunchKernelGGL(k3_bcast, dim3(4096), dim3(256), 0, stream, hxs, cxf, out);
}